// Round 7
// baseline (377.416 us; speedup 1.0000x reference)
//
#include <hip/hip_runtime.h>
#include <math.h>

#define NV 778
#define KROW 2334     // NV*3
#define KTOT 146      // 10 beta + 135 pose-feature + 1 const(template)
#define NCOL 1008     // 21 j * 16 jj * 3 c
#define NPART 32      // v-splits in PK build (25 verts each)
#define DTLD 160      // padded leading dim of transposed dirs
#define PEXLD 1032    // 21*49 + pad, epilogue LDS row stride

// L1 block ranges
#define NB_RED 12                     // 48 (j,c) reduction tasks, 4 waves/block
#define NB_Q   84                     // 336 Q tasks, 4 waves/block
#define NB_W2  ((NV*336 + 255)/256)   // 1022
#define NB_DT  NV                     // 778
#define NB_Z   ((KTOT*NCOL + 255)/256)// 575

// ======================= L1: ALL batch-independent precompute ================
// one launch, 256 threads/block:
//  [0,12)        SJ[k][j][c], J0[j][c]    (4 wave-tasks per block)
//  [12,96)       Q[j*16+jj]               (4 wave-tasks per block)
//  [96,1118)     W2[v][j*16+jj] = Jreg[v][j]*wgt[v][jj]
//  [1118,1896)   DT[c][v][k] = dirs_k[3v+c]
//  [1896,2471)   PK zero (atomic target for k_mid)
__global__ __launch_bounds__(256) void kA_all(const float* __restrict__ shapedirs,
                                              const float* __restrict__ posedirs,
                                              const float* __restrict__ v_template,
                                              const float* __restrict__ Jreg,
                                              const float* __restrict__ wgt,
                                              float* __restrict__ SJ, float* __restrict__ J0,
                                              float* __restrict__ Q,  float* __restrict__ W2,
                                              float* __restrict__ DT, float* __restrict__ PK)
{
    const int bid = blockIdx.x;
    const int t = threadIdx.x;
    const int wv = t >> 6, lane = t & 63;

    if (bid < NB_RED) {
        const int m = bid*4 + wv;            // 0..47
        const int j = m / 3, c = m % 3;
        float acc[11];
#pragma unroll
        for (int k = 0; k < 11; ++k) acc[k] = 0.f;
        for (int v = lane; v < NV; v += 64) {
            const float jr = Jreg[v*21 + j];
            acc[10] += v_template[v*3 + c] * jr;
#pragma unroll
            for (int k = 0; k < 10; ++k)
                acc[k] += shapedirs[(size_t)k*KROW + v*3 + c] * jr;
        }
#pragma unroll
        for (int k = 0; k < 11; ++k) {
            float s = acc[k];
#pragma unroll
            for (int off = 32; off >= 1; off >>= 1) s += __shfl_down(s, off, 64);
            acc[k] = s;
        }
        if (lane == 0) {
#pragma unroll
            for (int k = 0; k < 10; ++k) SJ[k*48 + j*3 + c] = acc[k];
            J0[j*3 + c] = acc[10];
        }
    } else if (bid < NB_RED + NB_Q) {
        const int m = (bid - NB_RED)*4 + wv; // 0..335
        const int j = m >> 4, jj = m & 15;
        float s = 0.f;
        for (int v = lane; v < NV; v += 64)
            s += Jreg[v*21 + j] * wgt[v*16 + jj];
#pragma unroll
        for (int off = 32; off >= 1; off >>= 1) s += __shfl_down(s, off, 64);
        if (lane == 0) Q[m] = s;
    } else if (bid < NB_RED + NB_Q + NB_W2) {
        const int gi = (bid - NB_RED - NB_Q)*256 + t;
        if (gi < NV*336) {
            const int v = gi / 336, m = gi % 336;
            const int j = m >> 4, jj = m & 15;
            W2[gi] = Jreg[v*21 + j] * wgt[v*16 + jj];
        }
    } else if (bid < NB_RED + NB_Q + NB_W2 + NB_DT) {
        const int v = bid - NB_RED - NB_Q - NB_W2;
        const int k = t;
        if (k < KTOT) {
            const float* drow = (k < 10)  ? shapedirs + (size_t)k*KROW
                              : (k < 145) ? posedirs + (size_t)(k-10)*KROW
                                          : v_template;
            DT[((size_t)0*NV + v)*DTLD + k] = drow[3*v + 0];
            DT[((size_t)1*NV + v)*DTLD + k] = drow[3*v + 1];
            DT[((size_t)2*NV + v)*DTLD + k] = drow[3*v + 2];
        }
    } else {
        const int idx = (bid - NB_RED - NB_Q - NB_W2 - NB_DT)*256 + t;
        if (idx < KTOT*NCOL) PK[idx] = 0.f;
    }
}

// ======================= L2: k_pre2 (atomic into PK)  ||  k2_pose ============
// bid < 2016 : PK[k][j*48+jj*3+c] += sum_{v in split s} DT[c][v][k]*W2[v][j*16+jj]
// else       : k2_pose block (bid-2016), verbatim pose/chain/coefT logic.
// The two halves are independent -> pose math overlaps the PK build.
__global__ __launch_bounds__(256) void k_mid(const float* __restrict__ DT,
                                             const float* __restrict__ W2,
                                             float* __restrict__ PK,
                                             const float* __restrict__ beta,
                                             const float* __restrict__ theta,
                                             const float* __restrict__ wrist,
                                             const float* __restrict__ hc,
                                             const float* __restrict__ hm,
                                             const float* __restrict__ SJ,
                                             const float* __restrict__ J0,
                                             float* __restrict__ coefT,
                                             float* __restrict__ A_g, int B)
{
    __shared__ float Rs[16*144];    // [b_loc][i*9+q]   (k2 half only)
    __shared__ float cls[16*148];   // [b_loc][k]
    const int bid = blockIdx.x;
    const int t = threadIdx.x;

    if (bid < 21*3*NPART) {
        // ---------------- PK build (atomic) ----------------
        const int j = bid % 21;
        const int c = (bid / 21) % 3;
        const int s = bid / 63;
        const int k = t;
        if (k >= KTOT) return;
        float acc[16];
#pragma unroll
        for (int q = 0; q < 16; ++q) acc[q] = 0.f;
        const int v0 = s*25, v1 = min(NV, v0 + 25);
        const float* dt = DT + ((size_t)c*NV)*DTLD + k;
        for (int v = v0; v < v1; ++v) {
            const float d = dt[(size_t)v*DTLD];                              // coalesced
            const float4* wq = (const float4*)(W2 + (size_t)v*336 + j*16);   // uniform
            const float4 w0 = wq[0], w1 = wq[1], w2 = wq[2], w3 = wq[3];
            acc[0]  += d*w0.x; acc[1]  += d*w0.y; acc[2]  += d*w0.z; acc[3]  += d*w0.w;
            acc[4]  += d*w1.x; acc[5]  += d*w1.y; acc[6]  += d*w1.z; acc[7]  += d*w1.w;
            acc[8]  += d*w2.x; acc[9]  += d*w2.y; acc[10] += d*w2.z; acc[11] += d*w2.w;
            acc[12] += d*w3.x; acc[13] += d*w3.y; acc[14] += d*w3.z; acc[15] += d*w3.w;
        }
        float* o = PK + (size_t)k*NCOL + j*48 + c;
#pragma unroll
        for (int q = 0; q < 16; ++q) atomicAdd(o + q*3, acc[q]);
        return;
    }

    // ---------------- k2_pose ----------------
    const int kb = bid - 21*3*NPART;
    const int bl = t >> 4, i = t & 15;
    const int b = kb*16 + bl;

    float r0, r1, r2;
    if (i == 0) {
        r0 = wrist[b*3+0]; r1 = wrist[b*3+1]; r2 = wrist[b*3+2];
#pragma unroll
        for (int k = 0; k < 10; ++k) cls[bl*148 + k] = beta[b*10 + k];
        cls[bl*148 + 145] = 1.0f;
    } else {
        const int col = (i-1)*3;
        float e0 = hm[col], e1 = hm[col+1], e2 = hm[col+2];
#pragma unroll
        for (int k = 0; k < 10; ++k) {
            const float th = theta[b*10 + k];
            e0 += th * hc[k*45 + col];
            e1 += th * hc[k*45 + col+1];
            e2 += th * hc[k*45 + col+2];
        }
        r0 = e0; r1 = e1; r2 = e2;
    }
    const float x_ = r0 + 1e-8f, y_ = r1 + 1e-8f, z_ = r2 + 1e-8f;
    const float angle = sqrtf(x_*x_ + y_*y_ + z_*z_);
    const float inv = 1.0f / angle;
    const float x = r0*inv, y = r1*inv, z = r2*inv;
    const float sn = sinf(angle), cs = cosf(angle);
    const float t1 = 1.0f - cs;
    float R[9];
    R[0] = 1.f - t1*(y*y + z*z);
    R[1] = -sn*z + t1*x*y;
    R[2] =  sn*y + t1*x*z;
    R[3] =  sn*z + t1*x*y;
    R[4] = 1.f - t1*(x*x + z*z);
    R[5] = -sn*x + t1*y*z;
    R[6] = -sn*y + t1*x*z;
    R[7] =  sn*x + t1*y*z;
    R[8] = 1.f - t1*(x*x + y*y);
#pragma unroll
    for (int q = 0; q < 9; ++q) Rs[bl*144 + i*9 + q] = R[q];
    if (i > 0) {
#pragma unroll
        for (int q = 0; q < 9; ++q)
            cls[bl*148 + 10 + (i-1)*9 + q] = R[q] - ((q==0||q==4||q==8) ? 1.f : 0.f);
    }
    __syncthreads();

    if (t < KTOT) {
        float tmp[16];
#pragma unroll
        for (int m = 0; m < 16; ++m) tmp[m] = cls[m*148 + t];
        float4* dst = (float4*)(coefT + (size_t)t*B + kb*16);
        dst[0] = make_float4(tmp[0],  tmp[1],  tmp[2],  tmp[3]);
        dst[1] = make_float4(tmp[4],  tmp[5],  tmp[6],  tmp[7]);
        dst[2] = make_float4(tmp[8],  tmp[9],  tmp[10], tmp[11]);
        dst[3] = make_float4(tmp[12], tmp[13], tmp[14], tmp[15]);
    }

    if (t < 16) {
        const int b2 = kb*16 + t;
        float bt[10];
#pragma unroll
        for (int k = 0; k < 10; ++k) bt[k] = beta[b2*10 + k];
        const float* Rb = Rs + t*144;
        float4* Ab = (float4*)(A_g + (size_t)b2*192);

        auto jointJ = [&](int j, float* o) {
            float j0 = J0[j*3+0], j1 = J0[j*3+1], j2 = J0[j*3+2];
#pragma unroll
            for (int k = 0; k < 10; ++k) {
                j0 += bt[k] * SJ[k*48 + j*3 + 0];
                j1 += bt[k] * SJ[k*48 + j*3 + 1];
                j2 += bt[k] * SJ[k*48 + j*3 + 2];
            }
            o[0] = j0; o[1] = j1; o[2] = j2;
        };

        float G0R[9], J0v[3];
#pragma unroll
        for (int q = 0; q < 9; ++q) G0R[q] = Rb[q];
        jointJ(0, J0v);
#pragma unroll
        for (int r = 0; r < 3; ++r) {
            const float at = J0v[r] - (G0R[r*3+0]*J0v[0] + G0R[r*3+1]*J0v[1] + G0R[r*3+2]*J0v[2]);
            Ab[r] = make_float4(G0R[r*3+0], G0R[r*3+1], G0R[r*3+2], at);
        }
        for (int ch = 0; ch < 5; ++ch) {
            float GpR[9], Gpt[3], Jp[3];
#pragma unroll
            for (int q = 0; q < 9; ++q) GpR[q] = G0R[q];
            Gpt[0]=J0v[0]; Gpt[1]=J0v[1]; Gpt[2]=J0v[2];
            Jp[0]=J0v[0];  Jp[1]=J0v[1];  Jp[2]=J0v[2];
            for (int s = 0; s < 3; ++s) {
                const int j = ch*3 + 1 + s;
                float Rl[9];
                const float* Rj = Rb + j*9;
#pragma unroll
                for (int q = 0; q < 9; ++q) Rl[q] = Rj[q];
                float Jc[3];
                jointJ(j, Jc);
                const float tl0 = Jc[0]-Jp[0], tl1 = Jc[1]-Jp[1], tl2 = Jc[2]-Jp[2];
                float GR[9], Gt[3];
#pragma unroll
                for (int r = 0; r < 3; ++r) {
#pragma unroll
                    for (int cc = 0; cc < 3; ++cc)
                        GR[r*3+cc] = GpR[r*3+0]*Rl[0*3+cc] + GpR[r*3+1]*Rl[1*3+cc] + GpR[r*3+2]*Rl[2*3+cc];
                    Gt[r] = GpR[r*3+0]*tl0 + GpR[r*3+1]*tl1 + GpR[r*3+2]*tl2 + Gpt[r];
                }
#pragma unroll
                for (int r = 0; r < 3; ++r) {
                    const float at = Gt[r] - (GR[r*3+0]*Jc[0] + GR[r*3+1]*Jc[1] + GR[r*3+2]*Jc[2]);
                    Ab[j*3 + r] = make_float4(GR[r*3+0], GR[r*3+1], GR[r*3+2], at);
                }
#pragma unroll
                for (int q = 0; q < 9; ++q) GpR[q] = GR[q];
                Gpt[0]=Gt[0]; Gpt[1]=Gt[1]; Gpt[2]=Gt[2];
                Jp[0]=Jc[0];  Jp[1]=Jc[1];  Jp[2]=Jc[2];
            }
        }
    }
}

// ======================= k3: P-GEMM (B x 1008 x 146) + fused joint epilogue ==
// v2 shape (measured best 43.3 us): 512 thr, 2 cols/lane, 16 batches/block,
// grid B/16 = 512 = 2 blocks/CU. coef[k][b0..b0+15] block-uniform ->
// s_load_dwordx4 into SGPRs; PK read one coalesced float2 per lane per k.
__global__ __launch_bounds__(512) void k3_gemm(const float* __restrict__ coefT,
                                               const float* __restrict__ PK,
                                               const float* __restrict__ A_g,
                                               const float* __restrict__ Q,
                                               float* __restrict__ out, int B)
{
    __shared__ float Pex[8*PEXLD];       // 33 KB
    const int t  = threadIdx.x;
    const int b0 = blockIdx.x * 16;
    const int l  = t;                    // col-pair owner (l < 504)

    float acc[2][16];
#pragma unroll
    for (int e = 0; e < 16; ++e) { acc[0][e] = 0.f; acc[1][e] = 0.f; }

    if (l < 504) {
        const float* pkp = PK + 2*l;            // per-lane, 8B coalesced
        const float* cof = coefT + b0;          // block-uniform -> s_load
#pragma unroll 2
        for (int k = 0; k < KTOT; ++k) {
            const float2 p2 = *(const float2*)(pkp + (size_t)k*NCOL);
            const float4* cp = (const float4*)(cof + (size_t)k*B);
            const float4 c0 = cp[0], c1 = cp[1], c2 = cp[2], c3 = cp[3];
            const float cv[16] = {c0.x,c0.y,c0.z,c0.w, c1.x,c1.y,c1.z,c1.w,
                                  c2.x,c2.y,c2.z,c2.w, c3.x,c3.y,c3.z,c3.w};
#pragma unroll
            for (int e = 0; e < 16; ++e) {
                acc[0][e] += p2.x * cv[e];
                acc[1][e] += p2.y * cv[e];
            }
        }
    }

#pragma unroll
    for (int r = 0; r < 2; ++r) {        // fully unrolled: acc indices static
        __syncthreads();
        if (l < 504) {
            const int j  = (2*l) / 48;           // both cols in same j (2l even)
            const int sc = j*49 + (2*l - 48*j);  // padded col index
#pragma unroll
            for (int bb = 0; bb < 8; ++bb)
                *(float2*)(&Pex[bb*PEXLD + sc]) =
                    make_float2(acc[0][r*8 + bb], acc[1][r*8 + bb]);
        }
        __syncthreads();
        if (t < 504) {
            const int bl = t / 63;               // 0..7
            const int rm = t % 63;               // j*3+p
            const int j  = rm / 3, p = rm % 3;
            const int b  = b0 + r*8 + bl;
            const float4* Ab = ((const float4*)A_g) + (size_t)b*48;
            const float* Pr = Pex + bl*PEXLD + j*49;
            float s = 0.f;
#pragma unroll
            for (int jj = 0; jj < 16; ++jj) {
                const float4 a = Ab[jj*3 + p];
                s += a.x*Pr[jj*3+0] + a.y*Pr[jj*3+1] + a.z*Pr[jj*3+2]
                   + a.w*Q[j*16+jj];
            }
            out[(size_t)b0*63 + r*504 + t] = s;  // == b*63 + j*3 + p
        }
    }
}

// ============================================================================
extern "C" void kernel_launch(void* const* d_in, const int* in_sizes, int n_in,
                              void* d_out, int out_size, void* d_ws, size_t ws_size,
                              hipStream_t stream) {
    (void)n_in; (void)out_size; (void)ws_size;
    const float* beta       = (const float*)d_in[0];
    const float* theta      = (const float*)d_in[1];
    const float* wrist      = (const float*)d_in[2];
    const float* v_template = (const float*)d_in[3];
    const float* shapedirs  = (const float*)d_in[4];
    const float* posedirs   = (const float*)d_in[5];
    const float* Jreg       = (const float*)d_in[6];
    const float* hc         = (const float*)d_in[7];
    const float* hm         = (const float*)d_in[8];
    const float* wgt        = (const float*)d_in[9];
    float* out = (float*)d_out;
    const int B = in_sizes[0] / 10;

    // workspace layout (floats, offsets rounded to 64)
    float* ws = (float*)d_ws;
    size_t off = 0;
    auto alloc = [&](size_t n) { float* p = ws + off; off = (off + n + 63) & ~(size_t)63; return p; };
    float* SJ     = alloc(480);
    float* J0     = alloc(48);
    float* Q      = alloc(336);
    float* W2     = alloc((size_t)NV*336);
    float* DT     = alloc((size_t)3*NV*DTLD);
    float* PK     = alloc((size_t)KTOT*NCOL);
    float* coefT  = alloc((size_t)KTOT*B);
    float* A_g    = alloc((size_t)B*192);

    const int nb1 = NB_RED + NB_Q + NB_W2 + NB_DT + NB_Z;        // 2471
    const int nb2 = 21*3*NPART + (B + 15)/16;                    // 2016 + 512

    kA_all<<<nb1, 256, 0, stream>>>(shapedirs, posedirs, v_template, Jreg, wgt,
                                    SJ, J0, Q, W2, DT, PK);
    k_mid<<<nb2, 256, 0, stream>>>(DT, W2, PK, beta, theta, wrist, hc, hm,
                                   SJ, J0, coefT, A_g, B);
    k3_gemm<<<dim3(B/16), 512, 0, stream>>>(coefT, PK, A_g, Q, out, B);
}

// Round 8
// 165.378 us; speedup vs baseline: 2.2821x; 2.2821x over previous
//
#include <hip/hip_runtime.h>
#include <math.h>

#define NV 778
#define KROW 2334     // NV*3
#define KTOT 146      // 10 beta + 135 pose-feature + 1 const(template)
#define NCOL 1008     // 21 j * 16 jj * 3 c
#define NPART 32      // v-splits in PK build (25 verts each)
#define DTLD 160      // padded leading dim of transposed dirs
#define PEXLD 1032    // 21*49 + pad, epilogue LDS row stride

// ======================= kA: batch-independent precompute ====================
// bid <  48            : SJ[k][j][c], J0[j][c]   (chain joint regressors)
// bid <  384           : Q[j*16+jj] = sum_v Jreg[v][j]*wgt[v][jj]
// bid <  384+w2_blocks : W2[v][j*16+jj] = Jreg[v][j]*wgt[v][jj]
// else (NV blocks)     : DT[c][v][k] = dirs_k[3v+c]  (transposed dirs)
__global__ __launch_bounds__(64) void kA_pre(const float* __restrict__ shapedirs,
                                             const float* __restrict__ posedirs,
                                             const float* __restrict__ v_template,
                                             const float* __restrict__ Jreg,
                                             const float* __restrict__ wgt,
                                             float* __restrict__ SJ, float* __restrict__ J0,
                                             float* __restrict__ Q,  float* __restrict__ W2,
                                             float* __restrict__ DT, int w2_blocks)
{
    const int bid = blockIdx.x;
    const int t = threadIdx.x;
    if (bid < 48) {
        const int j = bid / 3, c = bid % 3;
        float acc[11];
#pragma unroll
        for (int k = 0; k < 11; ++k) acc[k] = 0.f;
        for (int v = t; v < NV; v += 64) {
            const float jr = Jreg[v*21 + j];
            acc[10] += v_template[v*3 + c] * jr;
#pragma unroll
            for (int k = 0; k < 10; ++k)
                acc[k] += shapedirs[(size_t)k*KROW + v*3 + c] * jr;
        }
#pragma unroll
        for (int k = 0; k < 11; ++k) {
            float s = acc[k];
#pragma unroll
            for (int off = 32; off >= 1; off >>= 1) s += __shfl_down(s, off, 64);
            acc[k] = s;
        }
        if (t == 0) {
#pragma unroll
            for (int k = 0; k < 10; ++k) SJ[k*48 + j*3 + c] = acc[k];
            J0[j*3 + c] = acc[10];
        }
    } else if (bid < 384) {
        const int m = bid - 48, j = m >> 4, jj = m & 15;
        float s = 0.f;
        for (int v = t; v < NV; v += 64)
            s += Jreg[v*21 + j] * wgt[v*16 + jj];
#pragma unroll
        for (int off = 32; off >= 1; off >>= 1) s += __shfl_down(s, off, 64);
        if (t == 0) Q[m] = s;
    } else if (bid < 384 + w2_blocks) {
        const int gi = (bid - 384)*64 + t;
        if (gi < NV*336) {
            const int v = gi / 336, m = gi % 336;
            const int j = m >> 4, jj = m & 15;
            W2[gi] = Jreg[v*21 + j] * wgt[v*16 + jj];
        }
    } else {
        const int v = bid - 384 - w2_blocks;   // one block per vertex
#pragma unroll
        for (int kk = 0; kk < 3; ++kk) {
            const int k = t + kk*64;
            if (k < KTOT) {
                const float* drow = (k < 10)  ? shapedirs + (size_t)k*KROW
                                  : (k < 145) ? posedirs + (size_t)(k-10)*KROW
                                              : v_template;
                DT[((size_t)0*NV + v)*DTLD + k] = drow[3*v + 0];
                DT[((size_t)1*NV + v)*DTLD + k] = drow[3*v + 1];
                DT[((size_t)2*NV + v)*DTLD + k] = drow[3*v + 2];
            }
        }
    }
}

// ======================= k_mid: k_pre2 (-> PKpart)  ||  k2_pose ==============
// bid < 2016 : PKpart[s][k][j*48+jj*3+c] = sum_{v in split s} DT[c][v][k]*W2[v][j*16+jj]
//              (NO atomics -- partials buffer, reduced by k_p3. R7's atomicAdd
//               variant was 258 us / 158 MB writes; never again.)
// else       : k2_pose block (bid-2016): rodrigues + coefT + kinematic chain.
// Halves are independent -> pose math overlaps the PK build off the critical path.
__global__ __launch_bounds__(256) void k_mid(const float* __restrict__ DT,
                                             const float* __restrict__ W2,
                                             float* __restrict__ PKpart,
                                             const float* __restrict__ beta,
                                             const float* __restrict__ theta,
                                             const float* __restrict__ wrist,
                                             const float* __restrict__ hc,
                                             const float* __restrict__ hm,
                                             const float* __restrict__ SJ,
                                             const float* __restrict__ J0,
                                             float* __restrict__ coefT,
                                             float* __restrict__ A_g, int B)
{
    __shared__ float Rs[16*144];    // [b_loc][i*9+q]   (k2 half only)
    __shared__ float cls[16*148];   // [b_loc][k]
    const int bid = blockIdx.x;
    const int t = threadIdx.x;

    if (bid < 21*3*NPART) {
        // ---------------- PK partials (verbatim R3 k_pre2) ----------------
        const int j = bid % 21;
        const int c = (bid / 21) % 3;
        const int s = bid / 63;
        const int k = t;
        if (k >= KTOT) return;
        float acc[16];
#pragma unroll
        for (int q = 0; q < 16; ++q) acc[q] = 0.f;
        const int v0 = s*25, v1 = min(NV, v0 + 25);
        const float* dt = DT + ((size_t)c*NV)*DTLD + k;
        for (int v = v0; v < v1; ++v) {
            const float d = dt[(size_t)v*DTLD];                              // coalesced
            const float4* wq = (const float4*)(W2 + (size_t)v*336 + j*16);   // uniform
            const float4 w0 = wq[0], w1 = wq[1], w2 = wq[2], w3 = wq[3];
            acc[0]  += d*w0.x; acc[1]  += d*w0.y; acc[2]  += d*w0.z; acc[3]  += d*w0.w;
            acc[4]  += d*w1.x; acc[5]  += d*w1.y; acc[6]  += d*w1.z; acc[7]  += d*w1.w;
            acc[8]  += d*w2.x; acc[9]  += d*w2.y; acc[10] += d*w2.z; acc[11] += d*w2.w;
            acc[12] += d*w3.x; acc[13] += d*w3.y; acc[14] += d*w3.z; acc[15] += d*w3.w;
        }
        float* o = PKpart + ((size_t)s*KTOT + k)*NCOL + j*48 + c;
#pragma unroll
        for (int q = 0; q < 16; ++q) o[q*3] = acc[q];
        return;
    }

    // ---------------- k2_pose (verbatim) ----------------
    const int kb = bid - 21*3*NPART;
    const int bl = t >> 4, i = t & 15;
    const int b = kb*16 + bl;

    float r0, r1, r2;
    if (i == 0) {
        r0 = wrist[b*3+0]; r1 = wrist[b*3+1]; r2 = wrist[b*3+2];
#pragma unroll
        for (int k = 0; k < 10; ++k) cls[bl*148 + k] = beta[b*10 + k];
        cls[bl*148 + 145] = 1.0f;
    } else {
        const int col = (i-1)*3;
        float e0 = hm[col], e1 = hm[col+1], e2 = hm[col+2];
#pragma unroll
        for (int k = 0; k < 10; ++k) {
            const float th = theta[b*10 + k];
            e0 += th * hc[k*45 + col];
            e1 += th * hc[k*45 + col+1];
            e2 += th * hc[k*45 + col+2];
        }
        r0 = e0; r1 = e1; r2 = e2;
    }
    const float x_ = r0 + 1e-8f, y_ = r1 + 1e-8f, z_ = r2 + 1e-8f;
    const float angle = sqrtf(x_*x_ + y_*y_ + z_*z_);
    const float inv = 1.0f / angle;
    const float x = r0*inv, y = r1*inv, z = r2*inv;
    const float sn = sinf(angle), cs = cosf(angle);
    const float t1 = 1.0f - cs;
    float R[9];
    R[0] = 1.f - t1*(y*y + z*z);
    R[1] = -sn*z + t1*x*y;
    R[2] =  sn*y + t1*x*z;
    R[3] =  sn*z + t1*x*y;
    R[4] = 1.f - t1*(x*x + z*z);
    R[5] = -sn*x + t1*y*z;
    R[6] = -sn*y + t1*x*z;
    R[7] =  sn*x + t1*y*z;
    R[8] = 1.f - t1*(x*x + y*y);
#pragma unroll
    for (int q = 0; q < 9; ++q) Rs[bl*144 + i*9 + q] = R[q];
    if (i > 0) {
#pragma unroll
        for (int q = 0; q < 9; ++q)
            cls[bl*148 + 10 + (i-1)*9 + q] = R[q] - ((q==0||q==4||q==8) ? 1.f : 0.f);
    }
    __syncthreads();

    if (t < KTOT) {
        float tmp[16];
#pragma unroll
        for (int m = 0; m < 16; ++m) tmp[m] = cls[m*148 + t];
        float4* dst = (float4*)(coefT + (size_t)t*B + kb*16);
        dst[0] = make_float4(tmp[0],  tmp[1],  tmp[2],  tmp[3]);
        dst[1] = make_float4(tmp[4],  tmp[5],  tmp[6],  tmp[7]);
        dst[2] = make_float4(tmp[8],  tmp[9],  tmp[10], tmp[11]);
        dst[3] = make_float4(tmp[12], tmp[13], tmp[14], tmp[15]);
    }

    if (t < 16) {
        const int b2 = kb*16 + t;
        float bt[10];
#pragma unroll
        for (int k = 0; k < 10; ++k) bt[k] = beta[b2*10 + k];
        const float* Rb = Rs + t*144;
        float4* Ab = (float4*)(A_g + (size_t)b2*192);

        auto jointJ = [&](int j, float* o) {
            float j0 = J0[j*3+0], j1 = J0[j*3+1], j2 = J0[j*3+2];
#pragma unroll
            for (int k = 0; k < 10; ++k) {
                j0 += bt[k] * SJ[k*48 + j*3 + 0];
                j1 += bt[k] * SJ[k*48 + j*3 + 1];
                j2 += bt[k] * SJ[k*48 + j*3 + 2];
            }
            o[0] = j0; o[1] = j1; o[2] = j2;
        };

        float G0R[9], J0v[3];
#pragma unroll
        for (int q = 0; q < 9; ++q) G0R[q] = Rb[q];
        jointJ(0, J0v);
#pragma unroll
        for (int r = 0; r < 3; ++r) {
            const float at = J0v[r] - (G0R[r*3+0]*J0v[0] + G0R[r*3+1]*J0v[1] + G0R[r*3+2]*J0v[2]);
            Ab[r] = make_float4(G0R[r*3+0], G0R[r*3+1], G0R[r*3+2], at);
        }
        for (int ch = 0; ch < 5; ++ch) {
            float GpR[9], Gpt[3], Jp[3];
#pragma unroll
            for (int q = 0; q < 9; ++q) GpR[q] = G0R[q];
            Gpt[0]=J0v[0]; Gpt[1]=J0v[1]; Gpt[2]=J0v[2];
            Jp[0]=J0v[0];  Jp[1]=J0v[1];  Jp[2]=J0v[2];
            for (int s = 0; s < 3; ++s) {
                const int j = ch*3 + 1 + s;
                float Rl[9];
                const float* Rj = Rb + j*9;
#pragma unroll
                for (int q = 0; q < 9; ++q) Rl[q] = Rj[q];
                float Jc[3];
                jointJ(j, Jc);
                const float tl0 = Jc[0]-Jp[0], tl1 = Jc[1]-Jp[1], tl2 = Jc[2]-Jp[2];
                float GR[9], Gt[3];
#pragma unroll
                for (int r = 0; r < 3; ++r) {
#pragma unroll
                    for (int cc = 0; cc < 3; ++cc)
                        GR[r*3+cc] = GpR[r*3+0]*Rl[0*3+cc] + GpR[r*3+1]*Rl[1*3+cc] + GpR[r*3+2]*Rl[2*3+cc];
                    Gt[r] = GpR[r*3+0]*tl0 + GpR[r*3+1]*tl1 + GpR[r*3+2]*tl2 + Gpt[r];
                }
#pragma unroll
                for (int r = 0; r < 3; ++r) {
                    const float at = Gt[r] - (GR[r*3+0]*Jc[0] + GR[r*3+1]*Jc[1] + GR[r*3+2]*Jc[2]);
                    Ab[j*3 + r] = make_float4(GR[r*3+0], GR[r*3+1], GR[r*3+2], at);
                }
#pragma unroll
                for (int q = 0; q < 9; ++q) GpR[q] = GR[q];
                Gpt[0]=Gt[0]; Gpt[1]=Gt[1]; Gpt[2]=Gt[2];
                Jp[0]=Jc[0];  Jp[1]=Jc[1];  Jp[2]=Jc[2];
            }
        }
    }
}

// ======================= k_p3: reduce partials -> PK[146][1008] (float4) =====
__global__ void k_p3(const float4* __restrict__ PKpart, float4* __restrict__ PK)
{
    const int n4 = KTOT*NCOL/4;          // 36792
    const int idx = blockIdx.x*256 + threadIdx.x;
    if (idx < n4) {
        float4 s = PKpart[idx];
#pragma unroll
        for (int p = 1; p < NPART; ++p) {
            const float4 v = PKpart[(size_t)p*n4 + idx];
            s.x += v.x; s.y += v.y; s.z += v.z; s.w += v.w;
        }
        PK[idx] = s;
    }
}

// ======================= k3: P-GEMM (B x 1008 x 146) + fused joint epilogue ==
// v2 shape (measured best 43.3 us): 512 thr, 2 cols/lane, 16 batches/block,
// grid B/16 = 512 = 2 blocks/CU. coef[k][b0..b0+15] block-uniform ->
// s_load_dwordx4 into SGPRs; PK read one coalesced float2 per lane per k.
__global__ __launch_bounds__(512) void k3_gemm(const float* __restrict__ coefT,
                                               const float* __restrict__ PK,
                                               const float* __restrict__ A_g,
                                               const float* __restrict__ Q,
                                               float* __restrict__ out, int B)
{
    __shared__ float Pex[8*PEXLD];       // 33 KB
    const int t  = threadIdx.x;
    const int b0 = blockIdx.x * 16;
    const int l  = t;                    // col-pair owner (l < 504)

    float acc[2][16];
#pragma unroll
    for (int e = 0; e < 16; ++e) { acc[0][e] = 0.f; acc[1][e] = 0.f; }

    if (l < 504) {
        const float* pkp = PK + 2*l;            // per-lane, 8B coalesced
        const float* cof = coefT + b0;          // block-uniform -> s_load
#pragma unroll 2
        for (int k = 0; k < KTOT; ++k) {
            const float2 p2 = *(const float2*)(pkp + (size_t)k*NCOL);
            const float4* cp = (const float4*)(cof + (size_t)k*B);
            const float4 c0 = cp[0], c1 = cp[1], c2 = cp[2], c3 = cp[3];
            const float cv[16] = {c0.x,c0.y,c0.z,c0.w, c1.x,c1.y,c1.z,c1.w,
                                  c2.x,c2.y,c2.z,c2.w, c3.x,c3.y,c3.z,c3.w};
#pragma unroll
            for (int e = 0; e < 16; ++e) {
                acc[0][e] += p2.x * cv[e];
                acc[1][e] += p2.y * cv[e];
            }
        }
    }

#pragma unroll
    for (int r = 0; r < 2; ++r) {        // fully unrolled: acc indices static
        __syncthreads();
        if (l < 504) {
            const int j  = (2*l) / 48;           // both cols in same j (2l even)
            const int sc = j*49 + (2*l - 48*j);  // padded col index
#pragma unroll
            for (int bb = 0; bb < 8; ++bb)
                *(float2*)(&Pex[bb*PEXLD + sc]) =
                    make_float2(acc[0][r*8 + bb], acc[1][r*8 + bb]);
        }
        __syncthreads();
        if (t < 504) {
            const int bl = t / 63;               // 0..7
            const int rm = t % 63;               // j*3+p
            const int j  = rm / 3, p = rm % 3;
            const int b  = b0 + r*8 + bl;
            const float4* Ab = ((const float4*)A_g) + (size_t)b*48;
            const float* Pr = Pex + bl*PEXLD + j*49;
            float s = 0.f;
#pragma unroll
            for (int jj = 0; jj < 16; ++jj) {
                const float4 a = Ab[jj*3 + p];
                s += a.x*Pr[jj*3+0] + a.y*Pr[jj*3+1] + a.z*Pr[jj*3+2]
                   + a.w*Q[j*16+jj];
            }
            out[(size_t)b0*63 + r*504 + t] = s;  // == b*63 + j*3 + p
        }
    }
}

// ============================================================================
extern "C" void kernel_launch(void* const* d_in, const int* in_sizes, int n_in,
                              void* d_out, int out_size, void* d_ws, size_t ws_size,
                              hipStream_t stream) {
    (void)n_in; (void)out_size; (void)ws_size;
    const float* beta       = (const float*)d_in[0];
    const float* theta      = (const float*)d_in[1];
    const float* wrist      = (const float*)d_in[2];
    const float* v_template = (const float*)d_in[3];
    const float* shapedirs  = (const float*)d_in[4];
    const float* posedirs   = (const float*)d_in[5];
    const float* Jreg       = (const float*)d_in[6];
    const float* hc         = (const float*)d_in[7];
    const float* hm         = (const float*)d_in[8];
    const float* wgt        = (const float*)d_in[9];
    float* out = (float*)d_out;
    const int B = in_sizes[0] / 10;

    // workspace layout (floats, offsets rounded to 64)
    float* ws = (float*)d_ws;
    size_t off = 0;
    auto alloc = [&](size_t n) { float* p = ws + off; off = (off + n + 63) & ~(size_t)63; return p; };
    float* SJ     = alloc(480);
    float* J0     = alloc(48);
    float* Q      = alloc(336);
    float* W2     = alloc((size_t)NV*336);
    float* DT     = alloc((size_t)3*NV*DTLD);
    float* PKpart = alloc((size_t)NPART*KTOT*NCOL);
    float* PK     = alloc((size_t)KTOT*NCOL);
    float* coefT  = alloc((size_t)KTOT*B);
    float* A_g    = alloc((size_t)B*192);

    const int w2_blocks = (NV*336 + 63)/64;
    const int nb_mid = 21*3*NPART + (B + 15)/16;   // 2016 pre2 + 512 pose

    kA_pre<<<384 + w2_blocks + NV, 64, 0, stream>>>(shapedirs, posedirs, v_template,
                                                    Jreg, wgt, SJ, J0, Q, W2, DT, w2_blocks);
    k_mid<<<nb_mid, 256, 0, stream>>>(DT, W2, PKpart, beta, theta, wrist, hc, hm,
                                      SJ, J0, coefT, A_g, B);
    k_p3<<<(KTOT*NCOL/4 + 255)/256, 256, 0, stream>>>((const float4*)PKpart, (float4*)PK);
    k3_gemm<<<dim3(B/16), 512, 0, stream>>>(coefT, PK, A_g, Q, out, B);
}

// Round 9
// 149.763 us; speedup vs baseline: 2.5201x; 1.1043x over previous
//
#include <hip/hip_runtime.h>
#include <math.h>

#define NV 778
#define KROW 2334     // NV*3
#define KTOT 146      // 10 beta + 135 pose-feature + 1 const(template)
#define KLD  148      // padded k-dim of PKpartT (multiple of 4)
#define NCOL 1008     // 21 j * 16 jj * 3 c
#define NPART 32      // v-splits in PK build (25 verts each)
#define DTLD 160      // padded leading dim of transposed dirs
#define PEXLD 1032    // 21*49 + pad, epilogue LDS row stride

// ======================= kA: batch-independent precompute ====================
// bid <  48            : SJ[k][j][c], J0[j][c]   (chain joint regressors)
// bid <  384           : Q[j*16+jj] = sum_v Jreg[v][j]*wgt[v][jj]
// bid <  384+w2_blocks : W2[v][j*16+jj] = Jreg[v][j]*wgt[v][jj]
// else (NV blocks)     : DT[c][v][k] = dirs_k[3v+c]  (transposed dirs)
__global__ __launch_bounds__(64) void kA_pre(const float* __restrict__ shapedirs,
                                             const float* __restrict__ posedirs,
                                             const float* __restrict__ v_template,
                                             const float* __restrict__ Jreg,
                                             const float* __restrict__ wgt,
                                             float* __restrict__ SJ, float* __restrict__ J0,
                                             float* __restrict__ Q,  float* __restrict__ W2,
                                             float* __restrict__ DT, int w2_blocks)
{
    const int bid = blockIdx.x;
    const int t = threadIdx.x;
    if (bid < 48) {
        const int j = bid / 3, c = bid % 3;
        float acc[11];
#pragma unroll
        for (int k = 0; k < 11; ++k) acc[k] = 0.f;
        for (int v = t; v < NV; v += 64) {
            const float jr = Jreg[v*21 + j];
            acc[10] += v_template[v*3 + c] * jr;
#pragma unroll
            for (int k = 0; k < 10; ++k)
                acc[k] += shapedirs[(size_t)k*KROW + v*3 + c] * jr;
        }
#pragma unroll
        for (int k = 0; k < 11; ++k) {
            float s = acc[k];
#pragma unroll
            for (int off = 32; off >= 1; off >>= 1) s += __shfl_down(s, off, 64);
            acc[k] = s;
        }
        if (t == 0) {
#pragma unroll
            for (int k = 0; k < 10; ++k) SJ[k*48 + j*3 + c] = acc[k];
            J0[j*3 + c] = acc[10];
        }
    } else if (bid < 384) {
        const int m = bid - 48, j = m >> 4, jj = m & 15;
        float s = 0.f;
        for (int v = t; v < NV; v += 64)
            s += Jreg[v*21 + j] * wgt[v*16 + jj];
#pragma unroll
        for (int off = 32; off >= 1; off >>= 1) s += __shfl_down(s, off, 64);
        if (t == 0) Q[m] = s;
    } else if (bid < 384 + w2_blocks) {
        const int gi = (bid - 384)*64 + t;
        if (gi < NV*336) {
            const int v = gi / 336, m = gi % 336;
            const int j = m >> 4, jj = m & 15;
            W2[gi] = Jreg[v*21 + j] * wgt[v*16 + jj];
        }
    } else {
        const int v = bid - 384 - w2_blocks;   // one block per vertex
#pragma unroll
        for (int kk = 0; kk < 3; ++kk) {
            const int k = t + kk*64;
            if (k < KTOT) {
                const float* drow = (k < 10)  ? shapedirs + (size_t)k*KROW
                                  : (k < 145) ? posedirs + (size_t)(k-10)*KROW
                                              : v_template;
                DT[((size_t)0*NV + v)*DTLD + k] = drow[3*v + 0];
                DT[((size_t)1*NV + v)*DTLD + k] = drow[3*v + 1];
                DT[((size_t)2*NV + v)*DTLD + k] = drow[3*v + 2];
            }
        }
    }
}

// ======================= k_mid: k_pre2 (-> PKpartT)  ||  k2_pose =============
// bid < 2016 : PKpartT[s][col][k] = sum_{v in split s} DT[c][v][k]*W2[v][j*16+jj]
//              col = j*48+jj*3+c. k-major layout: the store o[q*3*KLD] has
//              LANE STRIDE 4B (was 4032B row-major -> 64-line scatter per
//              store, 4.7M L2 transactions, the 46us/66MB-write pathology).
// else       : k2_pose block: rodrigues + coefT + kinematic chain.
__global__ __launch_bounds__(256) void k_mid(const float* __restrict__ DT,
                                             const float* __restrict__ W2,
                                             float* __restrict__ PKpartT,
                                             const float* __restrict__ beta,
                                             const float* __restrict__ theta,
                                             const float* __restrict__ wrist,
                                             const float* __restrict__ hc,
                                             const float* __restrict__ hm,
                                             const float* __restrict__ SJ,
                                             const float* __restrict__ J0,
                                             float* __restrict__ coefT,
                                             float* __restrict__ A_g, int B)
{
    __shared__ float Rs[16*144];    // [b_loc][i*9+q]   (k2 half only)
    __shared__ float cls[16*148];   // [b_loc][k]
    const int bid = blockIdx.x;
    const int t = threadIdx.x;

    if (bid < 21*3*NPART) {
        // ---------------- PK partials ----------------
        const int j = bid % 21;
        const int c = (bid / 21) % 3;
        const int s = bid / 63;
        const int k = t;
        if (k >= KTOT) return;
        float acc[16];
#pragma unroll
        for (int q = 0; q < 16; ++q) acc[q] = 0.f;
        const int v0 = s*25, v1 = min(NV, v0 + 25);
        const float* dt = DT + ((size_t)c*NV)*DTLD + k;
        for (int v = v0; v < v1; ++v) {
            const float d = dt[(size_t)v*DTLD];                              // coalesced
            const float4* wq = (const float4*)(W2 + (size_t)v*336 + j*16);   // uniform
            const float4 w0 = wq[0], w1 = wq[1], w2 = wq[2], w3 = wq[3];
            acc[0]  += d*w0.x; acc[1]  += d*w0.y; acc[2]  += d*w0.z; acc[3]  += d*w0.w;
            acc[4]  += d*w1.x; acc[5]  += d*w1.y; acc[6]  += d*w1.z; acc[7]  += d*w1.w;
            acc[8]  += d*w2.x; acc[9]  += d*w2.y; acc[10] += d*w2.z; acc[11] += d*w2.w;
            acc[12] += d*w3.x; acc[13] += d*w3.y; acc[14] += d*w3.z; acc[15] += d*w3.w;
        }
        // col-major store: col = j*48 + jj*3 + c, addr = (s*NCOL + col)*KLD + k
        float* o = PKpartT + ((size_t)s*NCOL + j*48 + c)*KLD + k;
#pragma unroll
        for (int q = 0; q < 16; ++q) o[(size_t)q*3*KLD] = acc[q];  // lane stride 4B
        return;
    }

    // ---------------- k2_pose (verbatim) ----------------
    const int kb = bid - 21*3*NPART;
    const int bl = t >> 4, i = t & 15;
    const int b = kb*16 + bl;

    float r0, r1, r2;
    if (i == 0) {
        r0 = wrist[b*3+0]; r1 = wrist[b*3+1]; r2 = wrist[b*3+2];
#pragma unroll
        for (int k = 0; k < 10; ++k) cls[bl*148 + k] = beta[b*10 + k];
        cls[bl*148 + 145] = 1.0f;
    } else {
        const int col = (i-1)*3;
        float e0 = hm[col], e1 = hm[col+1], e2 = hm[col+2];
#pragma unroll
        for (int k = 0; k < 10; ++k) {
            const float th = theta[b*10 + k];
            e0 += th * hc[k*45 + col];
            e1 += th * hc[k*45 + col+1];
            e2 += th * hc[k*45 + col+2];
        }
        r0 = e0; r1 = e1; r2 = e2;
    }
    const float x_ = r0 + 1e-8f, y_ = r1 + 1e-8f, z_ = r2 + 1e-8f;
    const float angle = sqrtf(x_*x_ + y_*y_ + z_*z_);
    const float inv = 1.0f / angle;
    const float x = r0*inv, y = r1*inv, z = r2*inv;
    const float sn = sinf(angle), cs = cosf(angle);
    const float t1 = 1.0f - cs;
    float R[9];
    R[0] = 1.f - t1*(y*y + z*z);
    R[1] = -sn*z + t1*x*y;
    R[2] =  sn*y + t1*x*z;
    R[3] =  sn*z + t1*x*y;
    R[4] = 1.f - t1*(x*x + z*z);
    R[5] = -sn*x + t1*y*z;
    R[6] = -sn*y + t1*x*z;
    R[7] =  sn*x + t1*y*z;
    R[8] = 1.f - t1*(x*x + y*y);
#pragma unroll
    for (int q = 0; q < 9; ++q) Rs[bl*144 + i*9 + q] = R[q];
    if (i > 0) {
#pragma unroll
        for (int q = 0; q < 9; ++q)
            cls[bl*148 + 10 + (i-1)*9 + q] = R[q] - ((q==0||q==4||q==8) ? 1.f : 0.f);
    }
    __syncthreads();

    if (t < KTOT) {
        float tmp[16];
#pragma unroll
        for (int m = 0; m < 16; ++m) tmp[m] = cls[m*148 + t];
        float4* dst = (float4*)(coefT + (size_t)t*B + kb*16);
        dst[0] = make_float4(tmp[0],  tmp[1],  tmp[2],  tmp[3]);
        dst[1] = make_float4(tmp[4],  tmp[5],  tmp[6],  tmp[7]);
        dst[2] = make_float4(tmp[8],  tmp[9],  tmp[10], tmp[11]);
        dst[3] = make_float4(tmp[12], tmp[13], tmp[14], tmp[15]);
    }

    if (t < 16) {
        const int b2 = kb*16 + t;
        float bt[10];
#pragma unroll
        for (int k = 0; k < 10; ++k) bt[k] = beta[b2*10 + k];
        const float* Rb = Rs + t*144;
        float4* Ab = (float4*)(A_g + (size_t)b2*192);

        auto jointJ = [&](int j, float* o) {
            float j0 = J0[j*3+0], j1 = J0[j*3+1], j2 = J0[j*3+2];
#pragma unroll
            for (int k = 0; k < 10; ++k) {
                j0 += bt[k] * SJ[k*48 + j*3 + 0];
                j1 += bt[k] * SJ[k*48 + j*3 + 1];
                j2 += bt[k] * SJ[k*48 + j*3 + 2];
            }
            o[0] = j0; o[1] = j1; o[2] = j2;
        };

        float G0R[9], J0v[3];
#pragma unroll
        for (int q = 0; q < 9; ++q) G0R[q] = Rb[q];
        jointJ(0, J0v);
#pragma unroll
        for (int r = 0; r < 3; ++r) {
            const float at = J0v[r] - (G0R[r*3+0]*J0v[0] + G0R[r*3+1]*J0v[1] + G0R[r*3+2]*J0v[2]);
            Ab[r] = make_float4(G0R[r*3+0], G0R[r*3+1], G0R[r*3+2], at);
        }
        for (int ch = 0; ch < 5; ++ch) {
            float GpR[9], Gpt[3], Jp[3];
#pragma unroll
            for (int q = 0; q < 9; ++q) GpR[q] = G0R[q];
            Gpt[0]=J0v[0]; Gpt[1]=J0v[1]; Gpt[2]=J0v[2];
            Jp[0]=J0v[0];  Jp[1]=J0v[1];  Jp[2]=J0v[2];
            for (int s = 0; s < 3; ++s) {
                const int j = ch*3 + 1 + s;
                float Rl[9];
                const float* Rj = Rb + j*9;
#pragma unroll
                for (int q = 0; q < 9; ++q) Rl[q] = Rj[q];
                float Jc[3];
                jointJ(j, Jc);
                const float tl0 = Jc[0]-Jp[0], tl1 = Jc[1]-Jp[1], tl2 = Jc[2]-Jp[2];
                float GR[9], Gt[3];
#pragma unroll
                for (int r = 0; r < 3; ++r) {
#pragma unroll
                    for (int cc = 0; cc < 3; ++cc)
                        GR[r*3+cc] = GpR[r*3+0]*Rl[0*3+cc] + GpR[r*3+1]*Rl[1*3+cc] + GpR[r*3+2]*Rl[2*3+cc];
                    Gt[r] = GpR[r*3+0]*tl0 + GpR[r*3+1]*tl1 + GpR[r*3+2]*tl2 + Gpt[r];
                }
#pragma unroll
                for (int r = 0; r < 3; ++r) {
                    const float at = Gt[r] - (GR[r*3+0]*Jc[0] + GR[r*3+1]*Jc[1] + GR[r*3+2]*Jc[2]);
                    Ab[j*3 + r] = make_float4(GR[r*3+0], GR[r*3+1], GR[r*3+2], at);
                }
#pragma unroll
                for (int q = 0; q < 9; ++q) GpR[q] = GR[q];
                Gpt[0]=Gt[0]; Gpt[1]=Gt[1]; Gpt[2]=Gt[2];
                Jp[0]=Jc[0];  Jp[1]=Jc[1];  Jp[2]=Jc[2];
            }
        }
    }
}

// ======= k_p3: reduce PKpartT[s][col][k] -> PK[k][col] (transpose) ==========
// Reads are float4-coalesced along k (the 32x-replicated side); writes are
// small scattered scalar stores (147K total, 32x fewer transactions than the
// old k_mid scatter). Padding rows k=146,147 are summed but never stored.
__global__ __launch_bounds__(256) void k_p3(const float4* __restrict__ PKpartT4,
                                            float* __restrict__ PK)
{
    const int n4s = NCOL*(KLD/4);        // 37296 float4 per split
    const int idx = blockIdx.x*256 + threadIdx.x;
    if (idx >= n4s) return;
    const int col = idx / (KLD/4);
    const int k4  = idx % (KLD/4);
    float4 s = PKpartT4[idx];
#pragma unroll
    for (int p = 1; p < NPART; ++p) {
        const float4 v = PKpartT4[(size_t)p*n4s + idx];
        s.x += v.x; s.y += v.y; s.z += v.z; s.w += v.w;
    }
    const int k = k4*4;
    const float sv[4] = {s.x, s.y, s.z, s.w};
#pragma unroll
    for (int e = 0; e < 4; ++e)
        if (k + e < KTOT) PK[(size_t)(k + e)*NCOL + col] = sv[e];
}

// ======================= k3: P-GEMM (B x 1008 x 146) + fused joint epilogue ==
// v2 shape (measured best 43.3 us): 512 thr, 2 cols/lane, 16 batches/block,
// grid B/16 = 512 = 2 blocks/CU. coef[k][b0..b0+15] block-uniform ->
// s_load_dwordx4 into SGPRs; PK read one coalesced float2 per lane per k.
__global__ __launch_bounds__(512) void k3_gemm(const float* __restrict__ coefT,
                                               const float* __restrict__ PK,
                                               const float* __restrict__ A_g,
                                               const float* __restrict__ Q,
                                               float* __restrict__ out, int B)
{
    __shared__ float Pex[8*PEXLD];       // 33 KB
    const int t  = threadIdx.x;
    const int b0 = blockIdx.x * 16;
    const int l  = t;                    // col-pair owner (l < 504)

    float acc[2][16];
#pragma unroll
    for (int e = 0; e < 16; ++e) { acc[0][e] = 0.f; acc[1][e] = 0.f; }

    if (l < 504) {
        const float* pkp = PK + 2*l;            // per-lane, 8B coalesced
        const float* cof = coefT + b0;          // block-uniform -> s_load
#pragma unroll 2
        for (int k = 0; k < KTOT; ++k) {
            const float2 p2 = *(const float2*)(pkp + (size_t)k*NCOL);
            const float4* cp = (const float4*)(cof + (size_t)k*B);
            const float4 c0 = cp[0], c1 = cp[1], c2 = cp[2], c3 = cp[3];
            const float cv[16] = {c0.x,c0.y,c0.z,c0.w, c1.x,c1.y,c1.z,c1.w,
                                  c2.x,c2.y,c2.z,c2.w, c3.x,c3.y,c3.z,c3.w};
#pragma unroll
            for (int e = 0; e < 16; ++e) {
                acc[0][e] += p2.x * cv[e];
                acc[1][e] += p2.y * cv[e];
            }
        }
    }

#pragma unroll
    for (int r = 0; r < 2; ++r) {        // fully unrolled: acc indices static
        __syncthreads();
        if (l < 504) {
            const int j  = (2*l) / 48;           // both cols in same j (2l even)
            const int sc = j*49 + (2*l - 48*j);  // padded col index
#pragma unroll
            for (int bb = 0; bb < 8; ++bb)
                *(float2*)(&Pex[bb*PEXLD + sc]) =
                    make_float2(acc[0][r*8 + bb], acc[1][r*8 + bb]);
        }
        __syncthreads();
        if (t < 504) {
            const int bl = t / 63;               // 0..7
            const int rm = t % 63;               // j*3+p
            const int j  = rm / 3, p = rm % 3;
            const int b  = b0 + r*8 + bl;
            const float4* Ab = ((const float4*)A_g) + (size_t)b*48;
            const float* Pr = Pex + bl*PEXLD + j*49;
            float s = 0.f;
#pragma unroll
            for (int jj = 0; jj < 16; ++jj) {
                const float4 a = Ab[jj*3 + p];
                s += a.x*Pr[jj*3+0] + a.y*Pr[jj*3+1] + a.z*Pr[jj*3+2]
                   + a.w*Q[j*16+jj];
            }
            out[(size_t)b0*63 + r*504 + t] = s;  // == b*63 + j*3 + p
        }
    }
}

// ============================================================================
extern "C" void kernel_launch(void* const* d_in, const int* in_sizes, int n_in,
                              void* d_out, int out_size, void* d_ws, size_t ws_size,
                              hipStream_t stream) {
    (void)n_in; (void)out_size; (void)ws_size;
    const float* beta       = (const float*)d_in[0];
    const float* theta      = (const float*)d_in[1];
    const float* wrist      = (const float*)d_in[2];
    const float* v_template = (const float*)d_in[3];
    const float* shapedirs  = (const float*)d_in[4];
    const float* posedirs   = (const float*)d_in[5];
    const float* Jreg       = (const float*)d_in[6];
    const float* hc         = (const float*)d_in[7];
    const float* hm         = (const float*)d_in[8];
    const float* wgt        = (const float*)d_in[9];
    float* out = (float*)d_out;
    const int B = in_sizes[0] / 10;

    // workspace layout (floats, offsets rounded to 64)
    float* ws = (float*)d_ws;
    size_t off = 0;
    auto alloc = [&](size_t n) { float* p = ws + off; off = (off + n + 63) & ~(size_t)63; return p; };
    float* SJ      = alloc(480);
    float* J0      = alloc(48);
    float* Q       = alloc(336);
    float* W2      = alloc((size_t)NV*336);
    float* DT      = alloc((size_t)3*NV*DTLD);
    float* PKpartT = alloc((size_t)NPART*NCOL*KLD);
    float* PK      = alloc((size_t)KTOT*NCOL);
    float* coefT   = alloc((size_t)KTOT*B);
    float* A_g     = alloc((size_t)B*192);

    const int w2_blocks = (NV*336 + 63)/64;
    const int nb_mid = 21*3*NPART + (B + 15)/16;   // 2016 pre2 + 512 pose
    const int nb_p3  = (NCOL*(KLD/4) + 255)/256;   // 146

    kA_pre<<<384 + w2_blocks + NV, 64, 0, stream>>>(shapedirs, posedirs, v_template,
                                                    Jreg, wgt, SJ, J0, Q, W2, DT, w2_blocks);
    k_mid<<<nb_mid, 256, 0, stream>>>(DT, W2, PKpartT, beta, theta, wrist, hc, hm,
                                      SJ, J0, coefT, A_g, B);
    k_p3<<<nb_p3, 256, 0, stream>>>((const float4*)PKpartT, PK);
    k3_gemm<<<dim3(B/16), 512, 0, stream>>>(coefT, PK, A_g, Q, out, B);
}